// Round 4
// baseline (336.606 us; speedup 1.0000x reference)
//
#include <hip/hip_runtime.h>
#include <cstdint>

#define BB 4
#define LL 512
#define DD 64
#define HH 128
#define NEGV -1000000000.0f
#define NBLK 256
#define NTHR 1024
#define NACT 64   // blocks active during sinkhorn iterations (16 per batch, 32 rows each)

// Monotonic grid barrier: counter zeroed by a hipMemsetAsync node before launch.
// Release on arrive publishes this block's global writes to device scope;
// acquire on the spin makes other blocks' writes visible (cross-XCD safe).
__device__ __forceinline__ void grid_barrier(unsigned* cnt, unsigned target) {
    __syncthreads();
    if (threadIdx.x == 0) {
        __hip_atomic_fetch_add(cnt, 1u, __ATOMIC_RELEASE, __HIP_MEMORY_SCOPE_AGENT);
        while (__hip_atomic_load(cnt, __ATOMIC_ACQUIRE, __HIP_MEMORY_SCOPE_AGENT) < target)
            __builtin_amdgcn_s_sleep(2);
    }
    __syncthreads();
}

__device__ __forceinline__ float hmax4(float4 v) {
    return fmaxf(fmaxf(v.x, v.y), fmaxf(v.z, v.w));
}

__global__ __launch_bounds__(NTHR) void mega(
    const float* __restrict__ etime, const int* __restrict__ etype,
    const float* __restrict__ x, const int* __restrict__ slens,
    const float* __restrict__ gum, const float* __restrict__ W1,
    const float* __restrict__ b1, const float* __restrict__ W2,
    const float* __restrict__ b2, float* __restrict__ out, float* __restrict__ ws)
{
    // LDS map (floats):
    //   [0,16384)      phase1: sp(8192)+sq(8192); then cbuf(16384); phase2: sla 32x512
    //   [16384,17408)  redm [2][512]
    //   [17408,18432)  reds [2][512]
    //   [18432,18944)  clse [512]
    //   [18944,19072)  sw2  [128]
    __shared__ float smem[19072];

    unsigned* cnt = (unsigned*)ws;
    float* piG  = ws + 64;                    // [2048][128]
    float* pjG  = piG + BB * LL * HH;         // [2048][128]
    float* laG  = pjG + BB * LL * HH;         // [4][512][512]
    float* cmG  = laG + (size_t)BB * LL * LL; // [2][4][32][512]
    float* csG  = cmG + 2 * BB * 32 * LL;     // [2][4][32][512]
    float* otyG = csG + 2 * BB * 32 * LL;     // [4][16][512]
    float* otmG = otyG + BB * 16 * LL;        // [4][16][512]

    const int t = threadIdx.x;
    const int bx = blockIdx.x;

    // ===================== Phase 0: pi = x@W1[:D]+b1, pj = x@W1[D:] ============
    {
        int gid = (bx << 10) + t;             // 262144 = 2048 rows x 128 h
        int row = gid >> 7;
        int h = gid & (HH - 1);
        const float* xr = x + row * DD;
        float ap = b1[h];
        float aq = 0.f;
        #pragma unroll 8
        for (int d = 0; d < DD; ++d) {
            float xv = xr[d];
            ap = fmaf(xv, W1[d * HH + h], ap);
            aq = fmaf(xv, W1[(DD + d) * HH + h], aq);
        }
        piG[row * HH + h] = ap;
        pjG[row * HH + h] = aq;
    }
    grid_barrier(cnt, 1 * NBLK);

    // ===================== Phase 1: scores -> la0 (masked, /tau) ===============
    {
        float* sp  = smem;
        float* sq  = smem + 8192;
        float* sw2 = smem + 18944;
        int jt = bx & 7, it8 = (bx >> 3) & 7, b = bx >> 6;
        int i0 = it8 << 6, j0 = jt << 6;
        int rowb = b * LL + i0, colb = b * LL + j0;

        #pragma unroll
        for (int k = 0; k < 2; ++k) {
            int flat = (k << 10) + t;          // 0..2047 quad slots
            int i = flat >> 5, q = flat & 31;
            int dq = q ^ ((i >> 2) & 7);       // XOR swizzle
            *(float4*)(sp + i * HH + (dq << 2)) =
                *(const float4*)(piG + (size_t)(rowb + i) * HH + (q << 2));
            *(float4*)(sq + i * HH + (dq << 2)) =
                *(const float4*)(pjG + (size_t)(colb + i) * HH + (q << 2));
        }
        if (t < HH) sw2[t] = W2[t];
        __syncthreads();

        // h split into 4 groups of 8 hq; each 256-thread group does a 4x4 micro-tile
        int hg = t >> 8, tt = t & 255;
        int w = tt >> 6, lane = tt & 63;
        int ti = ((w >> 1) << 3) + (lane >> 3);
        int tj = ((w & 1) << 3) + (lane & 7);
        int kti = ti & 7, ktj = tj & 7;

        float acc[4][4];
        #pragma unroll
        for (int a = 0; a < 4; ++a)
            #pragma unroll
            for (int c = 0; c < 4; ++c) acc[a][c] = 0.f;

        for (int hq = hg * 8; hq < hg * 8 + 8; ++hq) {
            float4 w4 = *(const float4*)(sw2 + (hq << 2));
            int offi = (hq ^ kti) << 2;
            int offj = (hq ^ ktj) << 2;
            float4 pa[4], pb[4];
            #pragma unroll
            for (int a = 0; a < 4; ++a) pa[a] = *(const float4*)(sp + (4*ti + a) * HH + offi);
            #pragma unroll
            for (int c = 0; c < 4; ++c) pb[c] = *(const float4*)(sq + (4*tj + c) * HH + offj);
            #pragma unroll
            for (int a = 0; a < 4; ++a) {
                #pragma unroll
                for (int c = 0; c < 4; ++c) {
                    float t0 = fmaxf(pa[a].x + pb[c].x, 0.f);
                    float t1 = fmaxf(pa[a].y + pb[c].y, 0.f);
                    float t2 = fmaxf(pa[a].z + pb[c].z, 0.f);
                    float t3 = fmaxf(pa[a].w + pb[c].w, 0.f);
                    float s = acc[a][c];
                    s += t0 * w4.x; s += t1 * w4.y; s += t2 * w4.z; s += t3 * w4.w;
                    acc[a][c] = s;
                }
            }
        }
        __syncthreads();                      // done with sp/sq
        float* cbuf = smem;                   // alias: [4 groups][256 tt][16]
        #pragma unroll
        for (int a = 0; a < 4; ++a)
            #pragma unroll
            for (int c = 0; c < 4; ++c)
                cbuf[(((hg << 8) + tt) << 4) + (a << 2) + c] = acc[a][c];
        __syncthreads();

        // combine h-groups + epilogue: thread -> (tt2, a2)
        int tt2 = t >> 2, a2 = t & 3;
        int w2_ = tt2 >> 6, lane2 = tt2 & 63;
        int ti2 = ((w2_ >> 1) << 3) + (lane2 >> 3);
        int tj2 = ((w2_ & 1) << 3) + (lane2 & 7);
        float4 o = make_float4(0.f, 0.f, 0.f, 0.f);
        #pragma unroll
        for (int g = 0; g < 4; ++g) {
            float4 pp = *(const float4*)(cbuf + (((g << 8) + tt2) << 4) + (a2 << 2));
            o.x += pp.x; o.y += pp.y; o.z += pp.z; o.w += pp.w;
        }
        int sl = slens[b];
        float bb2 = b2[0];
        int ig = i0 + 4 * ti2 + a2;
        int jb = j0 + 4 * tj2;
        float4 g4 = *(const float4*)(gum + ((size_t)(b * LL + ig)) * LL + jb);
        bool iv = ig < sl;
        float4 res;
        res.x = (iv && (jb + 0) < sl) ? (o.x + bb2 + g4.x) * 2.0f : NEGV;
        res.y = (iv && (jb + 1) < sl) ? (o.y + bb2 + g4.y) * 2.0f : NEGV;
        res.z = (iv && (jb + 2) < sl) ? (o.z + bb2 + g4.z) * 2.0f : NEGV;
        res.w = (iv && (jb + 3) < sl) ? (o.w + bb2 + g4.w) * 2.0f : NEGV;
        *(float4*)(laG + ((size_t)(b * LL + ig)) * LL + jb) = res;
    }
    grid_barrier(cnt, 2 * NBLK);

    // ===================== Phase 2: 10 Sinkhorn iterations =====================
    const bool active = bx < NACT;
    const int b2i = bx >> 4;
    const int stripe = bx & 15;
    const int r0 = stripe << 5;               // 32 rows per active block
    float* sla  = smem;                       // [32][512]
    float* redm = smem + 16384;               // [2][512]
    float* reds = smem + 17408;               // [2][512]
    float* clse = smem + 18432;               // [512]
    int sl_a = 0;

    if (active) {
        sl_a = slens[b2i];
        float4* sla4 = (float4*)sla;
        const float4* src4 = (const float4*)(laG + (((size_t)(b2i << 9) + r0) << 9));
        #pragma unroll
        for (int k = 0; k < 4; ++k) sla4[(k << 10) + t] = src4[(k << 10) + t];
        __syncthreads();
    }

    for (int it = 0; it < 10; ++it) {
        const int par = it & 1;
        const int last = (it == 9);
        if (active) {
            // ---- row LSE (block-local; 32 lanes per row) ----
            int r = t >> 5, cq = t & 31;
            float4 v[4];
            #pragma unroll
            for (int k = 0; k < 4; ++k)
                v[k] = *(float4*)(sla + (r << 9) + ((cq + (k << 5)) << 2));
            float m = fmaxf(fmaxf(hmax4(v[0]), hmax4(v[1])), fmaxf(hmax4(v[2]), hmax4(v[3])));
            #pragma unroll
            for (int off = 16; off; off >>= 1) m = fmaxf(m, __shfl_xor(m, off));
            float s = 0.f;
            #pragma unroll
            for (int k = 0; k < 4; ++k)
                s += __expf(v[k].x - m) + __expf(v[k].y - m) + __expf(v[k].z - m) + __expf(v[k].w - m);
            #pragma unroll
            for (int off = 16; off; off >>= 1) s += __shfl_xor(s, off);
            float lse = m + __logf(s);        // NEG-absorption preserved in fp32
            #pragma unroll
            for (int k = 0; k < 4; ++k) {
                v[k].x -= lse; v[k].y -= lse; v[k].z -= lse; v[k].w -= lse;
                *(float4*)(sla + (r << 9) + ((cq + (k << 5)) << 2)) = v[k];
            }
            __syncthreads();

            // ---- column partials over this block's 32 rows (2 subs of 16) ----
            int c = t & 511, half = t >> 9;
            float vv[16];
            #pragma unroll
            for (int rr = 0; rr < 16; ++rr) vv[rr] = sla[(((half << 4) + rr) << 9) + c];
            float mp = vv[0];
            #pragma unroll
            for (int rr = 1; rr < 16; ++rr) mp = fmaxf(mp, vv[rr]);
            float spv = 0.f;
            #pragma unroll
            for (int rr = 0; rr < 16; ++rr) spv += __expf(vv[rr] - mp);
            size_t pidx = ((((size_t)par * BB + b2i) << 5) + (stripe << 1) + half) * LL + c;
            cmG[pidx] = mp;
            csG[pidx] = spv;
        }
        grid_barrier(cnt, (3 + it) * NBLK);
        if (active) {
            // ---- combine 32 sub-partials (deterministic, redundant per block) --
            int c = t & 511, half = t >> 9;
            const float* cmB = cmG + ((((size_t)par * BB + b2i) << 5)) * LL;
            const float* csB = csG + ((((size_t)par * BB + b2i) << 5)) * LL;
            int g0 = half << 4;
            float mreg[16];
            #pragma unroll
            for (int g = 0; g < 16; ++g) mreg[g] = cmB[(g0 + g) * LL + c];
            float M = mreg[0];
            #pragma unroll
            for (int g = 1; g < 16; ++g) M = fmaxf(M, mreg[g]);
            redm[(half << 9) + c] = M;
            __syncthreads();
            float Mg = fmaxf(redm[c], redm[512 + c]);
            float S = 0.f;
            #pragma unroll
            for (int g = 0; g < 16; ++g)
                S = fmaf(csB[(g0 + g) * LL + c], __expf(mreg[g] - Mg), S);
            reds[(half << 9) + c] = S;
            __syncthreads();
            if (half == 0) clse[c] = Mg + __logf(reds[c] + reds[512 + c]);
            __syncthreads();

            // ---- subtract + re-mask (or finalize) ----
            int r = t >> 5, cq = t & 31;
            int grow = r0 + r;
            bool ivR = grow < sl_a;
            if (!last) {
                #pragma unroll
                for (int k = 0; k < 4; ++k) {
                    int cb = (cq + (k << 5)) << 2;
                    float4 v = *(float4*)(sla + (r << 9) + cb);
                    float4 l = *(const float4*)(clse + cb);
                    float4 o;
                    o.x = (ivR && (cb + 0) < sl_a) ? v.x - l.x : NEGV;
                    o.y = (ivR && (cb + 1) < sl_a) ? v.y - l.y : NEGV;
                    o.z = (ivR && (cb + 2) < sl_a) ? v.z - l.z : NEGV;
                    o.w = (ivR && (cb + 3) < sl_a) ? v.w - l.w : NEGV;
                    *(float4*)(sla + (r << 9) + cb) = o;
                }
                // next row-norm reads only this thread's own addresses; the
                // per-iteration __syncthreads above covers cross-thread reads.
            } else {
                float etf = (float)etype[(b2i << 9) + grow];
                float etv = etime[(b2i << 9) + grow];
                float4 p[4];
                #pragma unroll
                for (int k = 0; k < 4; ++k) {
                    int cb = (cq + (k << 5)) << 2;
                    float4 v = *(float4*)(sla + (r << 9) + cb);
                    float4 l = *(const float4*)(clse + cb);
                    float4 q;
                    q.x = (ivR && (cb + 0) < sl_a) ? __expf(v.x - l.x) : 0.f;
                    q.y = (ivR && (cb + 1) < sl_a) ? __expf(v.y - l.y) : 0.f;
                    q.z = (ivR && (cb + 2) < sl_a) ? __expf(v.z - l.z) : 0.f;
                    q.w = (ivR && (cb + 3) < sl_a) ? __expf(v.w - l.w) : 0.f;
                    p[k] = q;
                    *(float4*)(out + 2 * BB * LL + (((size_t)(b2i << 9) + grow) << 9) + cb) = q;
                }
                // type-weighted column partial (transpose via sla)
                #pragma unroll
                for (int k = 0; k < 4; ++k) {
                    int cb = (cq + (k << 5)) << 2;
                    *(float4*)(sla + (r << 9) + cb) =
                        make_float4(p[k].x * etf, p[k].y * etf, p[k].z * etf, p[k].w * etf);
                }
                __syncthreads();
                {
                    int c2 = t & 511, h2 = t >> 9;
                    float sA = 0.f;
                    #pragma unroll
                    for (int rr = 0; rr < 16; ++rr) sA += sla[(((h2 << 4) + rr) << 9) + c2];
                    redm[(h2 << 9) + c2] = sA;
                }
                __syncthreads();
                if (t < 512) otyG[((b2i << 4) + stripe) * LL + t] = redm[t] + redm[512 + t];
                __syncthreads();
                // time-weighted column partial
                #pragma unroll
                for (int k = 0; k < 4; ++k) {
                    int cb = (cq + (k << 5)) << 2;
                    *(float4*)(sla + (r << 9) + cb) =
                        make_float4(p[k].x * etv, p[k].y * etv, p[k].z * etv, p[k].w * etv);
                }
                __syncthreads();
                {
                    int c2 = t & 511, h2 = t >> 9;
                    float sB = 0.f;
                    #pragma unroll
                    for (int rr = 0; rr < 16; ++rr) sB += sla[(((h2 << 4) + rr) << 9) + c2];
                    reds[(h2 << 9) + c2] = sB;
                }
                __syncthreads();
                if (t < 512) otmG[((b2i << 4) + stripe) * LL + t] = reds[t] + reds[512 + t];
            }
        }
    }
    grid_barrier(cnt, 13 * NBLK);

    // ===================== Phase 3: combine output partials ====================
    if (bx < 64 && t < 32) {
        int b = bx >> 4, chunk = bx & 15;
        int c = (chunk << 5) + t;
        float a = 0.f, d = 0.f;
        #pragma unroll
        for (int s = 0; s < 16; ++s) {
            a += otyG[((b << 4) + s) * LL + c];
            d += otmG[((b << 4) + s) * LL + c];
        }
        out[(b << 9) + c] = a;                 // types_permed
        out[BB * LL + (b << 9) + c] = d;       // times_permed
    }
}

extern "C" void kernel_launch(void* const* d_in, const int* in_sizes, int n_in,
                              void* d_out, int out_size, void* d_ws, size_t ws_size,
                              hipStream_t stream)
{
    const float* etime = (const float*)d_in[0];
    const int*   etype = (const int*)d_in[1];
    const float* x     = (const float*)d_in[2];
    const int*   slens = (const int*)d_in[3];
    const float* gum   = (const float*)d_in[4];
    const float* W1    = (const float*)d_in[5];
    const float* b1    = (const float*)d_in[6];
    const float* W2    = (const float*)d_in[7];
    const float* b2    = (const float*)d_in[8];
    float* out = (float*)d_out;
    float* wsf = (float*)d_ws;

    // reset the grid-barrier counter (deterministic across graph replays)
    hipMemsetAsync(d_ws, 0, 256, stream);

    void* args[] = {(void*)&etime, (void*)&etype, (void*)&x, (void*)&slens, (void*)&gum,
                    (void*)&W1, (void*)&b1, (void*)&W2, (void*)&b2, (void*)&out, (void*)&wsf};
    hipError_t err = hipLaunchCooperativeKernel((const void*)mega, dim3(NBLK), dim3(NTHR),
                                                args, 0, stream);
    if (err != hipSuccess) {
        // 256 blocks x 1024 thr = exactly 1 block/CU on 256 CUs -> co-resident.
        mega<<<NBLK, NTHR, 0, stream>>>(etime, etype, x, slens, gum, W1, b1, W2, b2, out, wsf);
    }
}

// Round 5
// 212.484 us; speedup vs baseline: 1.5841x; 1.5841x over previous
//
#include <hip/hip_runtime.h>
#include <cstdint>

#define BB 4
#define LL 512
#define DD 64
#define HH 128
#define NEGV -1000000000.0f
#define NBLK 256
#define NTHR 1024
#define NACT 64   // blocks active during sinkhorn iterations (16 per batch, 32 rows each)

// Monotonic grid barrier. Arrival: fetch_add(RELEASE, agent) — writes back this
// block's dirty L2 once, publishing its global writes. Spin: RELAXED loads
// (sc1 load straight to the coherent L3 — NO per-poll buffer_inv; the round-4
// version used ACQUIRE polls, which invalidated the XCD L2 every iteration and
// thrashed the whole chip). One acquire fence after the spin makes remote
// writes visible.
__device__ __forceinline__ void grid_barrier(unsigned* cnt, unsigned target) {
    __syncthreads();
    if (threadIdx.x == 0) {
        __hip_atomic_fetch_add(cnt, 1u, __ATOMIC_RELEASE, __HIP_MEMORY_SCOPE_AGENT);
        while (__hip_atomic_load(cnt, __ATOMIC_RELAXED, __HIP_MEMORY_SCOPE_AGENT) < target)
            __builtin_amdgcn_s_sleep(1);
        __builtin_amdgcn_fence(__ATOMIC_ACQUIRE, "agent");
    }
    __syncthreads();
}

__device__ __forceinline__ float hmax4(float4 v) {
    return fmaxf(fmaxf(v.x, v.y), fmaxf(v.z, v.w));
}

__global__ __launch_bounds__(NTHR) void mega(
    const float* __restrict__ etime, const int* __restrict__ etype,
    const float* __restrict__ x, const int* __restrict__ slens,
    const float* __restrict__ gum, const float* __restrict__ W1,
    const float* __restrict__ b1, const float* __restrict__ W2,
    const float* __restrict__ b2, float* __restrict__ out, float* __restrict__ ws)
{
    // LDS map (floats):
    //   [0,16384)      phase1: sp(8192)+sq(8192); then cbuf(16384); phase2: sla 32x512
    //   [16384,17408)  redm [2][512]
    //   [17408,18432)  reds [2][512]
    //   [18432,18944)  clse [512]
    //   [18944,19072)  sw2  [128]
    __shared__ float smem[19072];

    unsigned* cntA = (unsigned*)ws;           // all-block barriers (phases 0,1)
    unsigned* cntB = (unsigned*)ws + 32;      // active-only barriers (iterations)
    float* piG  = ws + 64;                    // [2048][128]
    float* pjG  = piG + BB * LL * HH;         // [2048][128]
    float* laG  = pjG + BB * LL * HH;         // [4][512][512]
    float* cmG  = laG + (size_t)BB * LL * LL; // [2][4][32][512]
    float* csG  = cmG + 2 * BB * 32 * LL;     // [2][4][32][512]
    float* otyG = csG + 2 * BB * 32 * LL;     // [4][16][512]
    float* otmG = otyG + BB * 16 * LL;        // [4][16][512]

    const int t = threadIdx.x;
    const int bx = blockIdx.x;

    // ===================== Phase 0: pi = x@W1[:D]+b1, pj = x@W1[D:] ============
    {
        int gid = (bx << 10) + t;             // 262144 = 2048 rows x 128 h
        int row = gid >> 7;
        int h = gid & (HH - 1);
        const float* xr = x + row * DD;
        float ap = b1[h];
        float aq = 0.f;
        #pragma unroll 8
        for (int d = 0; d < DD; ++d) {
            float xv = xr[d];
            ap = fmaf(xv, W1[d * HH + h], ap);
            aq = fmaf(xv, W1[(DD + d) * HH + h], aq);
        }
        piG[row * HH + h] = ap;
        pjG[row * HH + h] = aq;
    }
    grid_barrier(cntA, 1 * NBLK);

    // ===================== Phase 1: scores -> la0 (masked, /tau) ===============
    {
        float* sp  = smem;
        float* sq  = smem + 8192;
        float* sw2 = smem + 18944;
        int jt = bx & 7, it8 = (bx >> 3) & 7, b = bx >> 6;
        int i0 = it8 << 6, j0 = jt << 6;
        int rowb = b * LL + i0, colb = b * LL + j0;

        #pragma unroll
        for (int k = 0; k < 2; ++k) {
            int flat = (k << 10) + t;          // 0..2047 quad slots
            int i = flat >> 5, q = flat & 31;
            int dq = q ^ ((i >> 2) & 7);       // XOR swizzle
            *(float4*)(sp + i * HH + (dq << 2)) =
                *(const float4*)(piG + (size_t)(rowb + i) * HH + (q << 2));
            *(float4*)(sq + i * HH + (dq << 2)) =
                *(const float4*)(pjG + (size_t)(colb + i) * HH + (q << 2));
        }
        if (t < HH) sw2[t] = W2[t];
        __syncthreads();

        // h split into 4 groups of 8 hq; each 256-thread group does a 4x4 micro-tile
        int hg = t >> 8, tt = t & 255;
        int w = tt >> 6, lane = tt & 63;
        int ti = ((w >> 1) << 3) + (lane >> 3);
        int tj = ((w & 1) << 3) + (lane & 7);
        int kti = ti & 7, ktj = tj & 7;

        float acc[4][4];
        #pragma unroll
        for (int a = 0; a < 4; ++a)
            #pragma unroll
            for (int c = 0; c < 4; ++c) acc[a][c] = 0.f;

        for (int hq = hg * 8; hq < hg * 8 + 8; ++hq) {
            float4 w4 = *(const float4*)(sw2 + (hq << 2));
            int offi = (hq ^ kti) << 2;
            int offj = (hq ^ ktj) << 2;
            float4 pa[4], pb[4];
            #pragma unroll
            for (int a = 0; a < 4; ++a) pa[a] = *(const float4*)(sp + (4*ti + a) * HH + offi);
            #pragma unroll
            for (int c = 0; c < 4; ++c) pb[c] = *(const float4*)(sq + (4*tj + c) * HH + offj);
            #pragma unroll
            for (int a = 0; a < 4; ++a) {
                #pragma unroll
                for (int c = 0; c < 4; ++c) {
                    float t0 = fmaxf(pa[a].x + pb[c].x, 0.f);
                    float t1 = fmaxf(pa[a].y + pb[c].y, 0.f);
                    float t2 = fmaxf(pa[a].z + pb[c].z, 0.f);
                    float t3 = fmaxf(pa[a].w + pb[c].w, 0.f);
                    float s = acc[a][c];
                    s += t0 * w4.x; s += t1 * w4.y; s += t2 * w4.z; s += t3 * w4.w;
                    acc[a][c] = s;
                }
            }
        }
        __syncthreads();                      // done with sp/sq
        float* cbuf = smem;                   // alias: [4 groups][256 tt][16]
        #pragma unroll
        for (int a = 0; a < 4; ++a)
            #pragma unroll
            for (int c = 0; c < 4; ++c)
                cbuf[(((hg << 8) + tt) << 4) + (a << 2) + c] = acc[a][c];
        __syncthreads();

        // combine h-groups + epilogue: thread -> (tt2, a2)
        int tt2 = t >> 2, a2 = t & 3;
        int w2_ = tt2 >> 6, lane2 = tt2 & 63;
        int ti2 = ((w2_ >> 1) << 3) + (lane2 >> 3);
        int tj2 = ((w2_ & 1) << 3) + (lane2 & 7);
        float4 o = make_float4(0.f, 0.f, 0.f, 0.f);
        #pragma unroll
        for (int g = 0; g < 4; ++g) {
            float4 pp = *(const float4*)(cbuf + (((g << 8) + tt2) << 4) + (a2 << 2));
            o.x += pp.x; o.y += pp.y; o.z += pp.z; o.w += pp.w;
        }
        int sl = slens[b];
        float bb2 = b2[0];
        int ig = i0 + 4 * ti2 + a2;
        int jb = j0 + 4 * tj2;
        float4 g4 = *(const float4*)(gum + ((size_t)(b * LL + ig)) * LL + jb);
        bool iv = ig < sl;
        float4 res;
        res.x = (iv && (jb + 0) < sl) ? (o.x + bb2 + g4.x) * 2.0f : NEGV;
        res.y = (iv && (jb + 1) < sl) ? (o.y + bb2 + g4.y) * 2.0f : NEGV;
        res.z = (iv && (jb + 2) < sl) ? (o.z + bb2 + g4.z) * 2.0f : NEGV;
        res.w = (iv && (jb + 3) < sl) ? (o.w + bb2 + g4.w) * 2.0f : NEGV;
        *(float4*)(laG + ((size_t)(b * LL + ig)) * LL + jb) = res;
    }
    grid_barrier(cntA, 2 * NBLK);

    // ===================== Phase 2: 10 Sinkhorn iterations =====================
    // Only 64 blocks participate; the rest exit now (no later work, no later
    // barriers for them) so iteration barriers sync 64 arrivals, not 256.
    if (bx >= NACT) return;

    const int b2i = bx >> 4;
    const int stripe = bx & 15;
    const int r0 = stripe << 5;               // 32 rows per active block
    float* sla  = smem;                       // [32][512]
    float* redm = smem + 16384;               // [2][512]
    float* reds = smem + 17408;               // [2][512]
    float* clse = smem + 18432;               // [512]
    const int sl_a = slens[b2i];

    {
        float4* sla4 = (float4*)sla;
        const float4* src4 = (const float4*)(laG + (((size_t)(b2i << 9) + r0) << 9));
        #pragma unroll
        for (int k = 0; k < 4; ++k) sla4[(k << 10) + t] = src4[(k << 10) + t];
        __syncthreads();
    }

    for (int it = 0; it < 10; ++it) {
        const int par = it & 1;
        const int last = (it == 9);
        {
            // ---- row LSE (block-local; 32 lanes per row) ----
            int r = t >> 5, cq = t & 31;
            float4 v[4];
            #pragma unroll
            for (int k = 0; k < 4; ++k)
                v[k] = *(float4*)(sla + (r << 9) + ((cq + (k << 5)) << 2));
            float m = fmaxf(fmaxf(hmax4(v[0]), hmax4(v[1])), fmaxf(hmax4(v[2]), hmax4(v[3])));
            #pragma unroll
            for (int off = 16; off; off >>= 1) m = fmaxf(m, __shfl_xor(m, off));
            float s = 0.f;
            #pragma unroll
            for (int k = 0; k < 4; ++k)
                s += __expf(v[k].x - m) + __expf(v[k].y - m) + __expf(v[k].z - m) + __expf(v[k].w - m);
            #pragma unroll
            for (int off = 16; off; off >>= 1) s += __shfl_xor(s, off);
            float lse = m + __logf(s);        // NEG-absorption preserved in fp32
            #pragma unroll
            for (int k = 0; k < 4; ++k) {
                v[k].x -= lse; v[k].y -= lse; v[k].z -= lse; v[k].w -= lse;
                *(float4*)(sla + (r << 9) + ((cq + (k << 5)) << 2)) = v[k];
            }
            __syncthreads();

            // ---- column partials over this block's 32 rows (2 subs of 16) ----
            int c = t & 511, half = t >> 9;
            float vv[16];
            #pragma unroll
            for (int rr = 0; rr < 16; ++rr) vv[rr] = sla[(((half << 4) + rr) << 9) + c];
            float mp = vv[0];
            #pragma unroll
            for (int rr = 1; rr < 16; ++rr) mp = fmaxf(mp, vv[rr]);
            float spv = 0.f;
            #pragma unroll
            for (int rr = 0; rr < 16; ++rr) spv += __expf(vv[rr] - mp);
            size_t pidx = ((((size_t)par * BB + b2i) << 5) + (stripe << 1) + half) * LL + c;
            cmG[pidx] = mp;
            csG[pidx] = spv;
        }
        grid_barrier(cntB, (it + 1) * NACT);
        {
            // ---- combine 32 sub-partials (deterministic, redundant per block) --
            int c = t & 511, half = t >> 9;
            const float* cmB = cmG + ((((size_t)par * BB + b2i) << 5)) * LL;
            const float* csB = csG + ((((size_t)par * BB + b2i) << 5)) * LL;
            int g0 = half << 4;
            float mreg[16];
            #pragma unroll
            for (int g = 0; g < 16; ++g) mreg[g] = cmB[(g0 + g) * LL + c];
            float M = mreg[0];
            #pragma unroll
            for (int g = 1; g < 16; ++g) M = fmaxf(M, mreg[g]);
            redm[(half << 9) + c] = M;
            __syncthreads();
            float Mg = fmaxf(redm[c], redm[512 + c]);
            float S = 0.f;
            #pragma unroll
            for (int g = 0; g < 16; ++g)
                S = fmaf(csB[(g0 + g) * LL + c], __expf(mreg[g] - Mg), S);
            reds[(half << 9) + c] = S;
            __syncthreads();
            if (half == 0) clse[c] = Mg + __logf(reds[c] + reds[512 + c]);
            __syncthreads();

            // ---- subtract + re-mask (or finalize) ----
            int r = t >> 5, cq = t & 31;
            int grow = r0 + r;
            bool ivR = grow < sl_a;
            if (!last) {
                #pragma unroll
                for (int k = 0; k < 4; ++k) {
                    int cb = (cq + (k << 5)) << 2;
                    float4 v = *(float4*)(sla + (r << 9) + cb);
                    float4 l = *(const float4*)(clse + cb);
                    float4 o;
                    o.x = (ivR && (cb + 0) < sl_a) ? v.x - l.x : NEGV;
                    o.y = (ivR && (cb + 1) < sl_a) ? v.y - l.y : NEGV;
                    o.z = (ivR && (cb + 2) < sl_a) ? v.z - l.z : NEGV;
                    o.w = (ivR && (cb + 3) < sl_a) ? v.w - l.w : NEGV;
                    *(float4*)(sla + (r << 9) + cb) = o;
                }
            } else {
                float etf = (float)etype[(b2i << 9) + grow];
                float etv = etime[(b2i << 9) + grow];
                float4 p[4];
                #pragma unroll
                for (int k = 0; k < 4; ++k) {
                    int cb = (cq + (k << 5)) << 2;
                    float4 v = *(float4*)(sla + (r << 9) + cb);
                    float4 l = *(const float4*)(clse + cb);
                    float4 q;
                    q.x = (ivR && (cb + 0) < sl_a) ? __expf(v.x - l.x) : 0.f;
                    q.y = (ivR && (cb + 1) < sl_a) ? __expf(v.y - l.y) : 0.f;
                    q.z = (ivR && (cb + 2) < sl_a) ? __expf(v.z - l.z) : 0.f;
                    q.w = (ivR && (cb + 3) < sl_a) ? __expf(v.w - l.w) : 0.f;
                    p[k] = q;
                    *(float4*)(out + 2 * BB * LL + (((size_t)(b2i << 9) + grow) << 9) + cb) = q;
                }
                // type-weighted column partial (transpose via sla)
                #pragma unroll
                for (int k = 0; k < 4; ++k) {
                    int cb = (cq + (k << 5)) << 2;
                    *(float4*)(sla + (r << 9) + cb) =
                        make_float4(p[k].x * etf, p[k].y * etf, p[k].z * etf, p[k].w * etf);
                }
                __syncthreads();
                {
                    int c2 = t & 511, h2 = t >> 9;
                    float sA = 0.f;
                    #pragma unroll
                    for (int rr = 0; rr < 16; ++rr) sA += sla[(((h2 << 4) + rr) << 9) + c2];
                    redm[(h2 << 9) + c2] = sA;
                }
                __syncthreads();
                if (t < 512) otyG[((b2i << 4) + stripe) * LL + t] = redm[t] + redm[512 + t];
                __syncthreads();
                // time-weighted column partial
                #pragma unroll
                for (int k = 0; k < 4; ++k) {
                    int cb = (cq + (k << 5)) << 2;
                    *(float4*)(sla + (r << 9) + cb) =
                        make_float4(p[k].x * etv, p[k].y * etv, p[k].z * etv, p[k].w * etv);
                }
                __syncthreads();
                {
                    int c2 = t & 511, h2 = t >> 9;
                    float sB = 0.f;
                    #pragma unroll
                    for (int rr = 0; rr < 16; ++rr) sB += sla[(((h2 << 4) + rr) << 9) + c2];
                    reds[(h2 << 9) + c2] = sB;
                }
                __syncthreads();
                if (t < 512) otmG[((b2i << 4) + stripe) * LL + t] = reds[t] + reds[512 + t];
            }
        }
    }
    grid_barrier(cntB, 11 * NACT);

    // ===================== Phase 3: combine output partials ====================
    if (t < 32) {
        int b = bx >> 4, chunk = bx & 15;
        int c = (chunk << 5) + t;
        float a = 0.f, d = 0.f;
        #pragma unroll
        for (int s = 0; s < 16; ++s) {
            a += otyG[((b << 4) + s) * LL + c];
            d += otmG[((b << 4) + s) * LL + c];
        }
        out[(b << 9) + c] = a;                 // types_permed
        out[BB * LL + (b << 9) + c] = d;       // times_permed
    }
}

extern "C" void kernel_launch(void* const* d_in, const int* in_sizes, int n_in,
                              void* d_out, int out_size, void* d_ws, size_t ws_size,
                              hipStream_t stream)
{
    const float* etime = (const float*)d_in[0];
    const int*   etype = (const int*)d_in[1];
    const float* x     = (const float*)d_in[2];
    const int*   slens = (const int*)d_in[3];
    const float* gum   = (const float*)d_in[4];
    const float* W1    = (const float*)d_in[5];
    const float* b1    = (const float*)d_in[6];
    const float* W2    = (const float*)d_in[7];
    const float* b2    = (const float*)d_in[8];
    float* out = (float*)d_out;
    float* wsf = (float*)d_ws;

    // reset the grid-barrier counters (deterministic across graph replays)
    hipMemsetAsync(d_ws, 0, 256, stream);

    void* args[] = {(void*)&etime, (void*)&etype, (void*)&x, (void*)&slens, (void*)&gum,
                    (void*)&W1, (void*)&b1, (void*)&W2, (void*)&b2, (void*)&out, (void*)&wsf};
    hipError_t err = hipLaunchCooperativeKernel((const void*)mega, dim3(NBLK), dim3(NTHR),
                                                args, 0, stream);
    if (err != hipSuccess) {
        // 256 blocks x 1024 thr = exactly 1 block/CU on 256 CUs -> co-resident.
        mega<<<NBLK, NTHR, 0, stream>>>(etime, etype, x, slens, gum, W1, b1, W2, b2, out, wsf);
    }
}

// Round 6
// 139.449 us; speedup vs baseline: 2.4138x; 1.5237x over previous
//
#include <hip/hip_runtime.h>
#include <cstdint>

#define BB 4
#define LL 512
#define DD 64
#define HH 128
#define NEGV -1000000000.0f
#define NBLK 256
#define NTHR 1024
#define NACT 64   // blocks active during sinkhorn iterations (16 per batch, 32 rows each)

// ---------------------------------------------------------------------------
// Coherent (write-through / read-through) 8B accessors. Relaxed agent-scope
// atomics lower to global_load/store_dwordx2 with sc0+sc1 — they bypass the
// non-coherent L2 and hit the chip-coherent L3 directly. ALL cross-block data
// uses these, so grid barriers need NO buffer_wbl2 / buffer_inv (the round-5
// killer: agent release/acquire = full 4MiB L2 writeback+invalidate walks,
// ~13us per barrier).
// ---------------------------------------------------------------------------
union U8 { unsigned long long u; float2 f; };

__device__ __forceinline__ float2 cload_f2(const float* p) {
    U8 v;
    v.u = __hip_atomic_load((const unsigned long long*)p,
                            __ATOMIC_RELAXED, __HIP_MEMORY_SCOPE_AGENT);
    return v.f;
}
__device__ __forceinline__ void cstore_f2(float* p, float2 x) {
    U8 v; v.f = x;
    __hip_atomic_store((unsigned long long*)p, v.u,
                       __ATOMIC_RELAXED, __HIP_MEMORY_SCOPE_AGENT);
}

// Light grid barrier: syncthreads drains every wave's vmcnt (sc1 store ack =
// visible at L3), leader does a relaxed fetch_add and relaxed polls. The
// workgroup-scope fences are waitcnt-only (no cache maintenance) and exist
// for compiler-level ordering of the surrounding coherent accesses.
__device__ __forceinline__ void grid_barrier(unsigned* cnt, unsigned target) {
    __builtin_amdgcn_fence(__ATOMIC_RELEASE, "workgroup");
    __syncthreads();
    if (threadIdx.x == 0) {
        __hip_atomic_fetch_add(cnt, 1u, __ATOMIC_RELAXED, __HIP_MEMORY_SCOPE_AGENT);
        while (__hip_atomic_load(cnt, __ATOMIC_RELAXED, __HIP_MEMORY_SCOPE_AGENT) < target)
            __builtin_amdgcn_s_sleep(1);
    }
    __builtin_amdgcn_fence(__ATOMIC_ACQUIRE, "workgroup");
    __syncthreads();
}

__device__ __forceinline__ float hmax4(float4 v) {
    return fmaxf(fmaxf(v.x, v.y), fmaxf(v.z, v.w));
}

__global__ __launch_bounds__(NTHR) void mega(
    const float* __restrict__ etime, const int* __restrict__ etype,
    const float* __restrict__ x, const int* __restrict__ slens,
    const float* __restrict__ gum, const float* __restrict__ W1,
    const float* __restrict__ b1, const float* __restrict__ W2,
    const float* __restrict__ b2, float* __restrict__ out, float* __restrict__ ws)
{
    // LDS map (floats):
    //   [0,16384)      phase1: sp(8192)+sq(8192); then cbuf(16384); phase2: sla 32x512
    //   [16384,17408)  redm [2][512]
    //   [17408,18432)  reds [2][512]
    //   [18432,18944)  clse [512]
    //   [18944,19072)  sw2  [128]
    __shared__ float smem[19072];

    unsigned* cntA = (unsigned*)ws;           // all-block barriers (phases 0,1)
    unsigned* cntB = (unsigned*)ws + 32;      // active-only barriers (iterations)
    float* piG   = ws + 64;                        // [2048][128]
    float* pjG   = piG + BB * LL * HH;             // [2048][128]
    float* laG   = pjG + BB * LL * HH;             // [4][512][512]
    float* cpkG  = laG + (size_t)BB * LL * LL;     // [2][4][32][512] x (m,s) pairs
    float* poutG = cpkG + 2 * BB * 32 * LL * 2;    // [4][16][512] x (ty,tm) pairs

    const int t = threadIdx.x;
    const int bx = blockIdx.x;

    // ===================== Phase 0: pi = x@W1[:D]+b1, pj = x@W1[D:] ============
    // 262144 threads -> 131072 (row, h-pair) outputs per array.
    {
        int gid = (bx << 10) + t;
        int arr = gid >> 17;               // 0: pi, 1: pj
        int rem = gid & 131071;
        int row = rem >> 6;                // 0..2047
        int h0  = (rem & 63) << 1;
        const float* xr = x + row * DD;
        const float* wb = W1 + (size_t)(arr * DD) * HH + h0;
        float a0 = arr ? 0.f : b1[h0];
        float a1 = arr ? 0.f : b1[h0 + 1];
        #pragma unroll 8
        for (int d = 0; d < DD; ++d) {
            float xv = xr[d];
            a0 = fmaf(xv, wb[d * HH + 0], a0);
            a1 = fmaf(xv, wb[d * HH + 1], a1);
        }
        float* dst = (arr ? pjG : piG) + (size_t)row * HH + h0;
        cstore_f2(dst, make_float2(a0, a1));
    }
    grid_barrier(cntA, 1 * NBLK);

    // ===================== Phase 1: scores -> la0 (masked, /tau) ===============
    {
        float* sp  = smem;
        float* sq  = smem + 8192;
        float* sw2 = smem + 18944;
        int jt = bx & 7, it8 = (bx >> 3) & 7, b = bx >> 6;
        int i0 = it8 << 6, j0 = jt << 6;
        int rowb = b * LL + i0, colb = b * LL + j0;

        // stage pi/pj tiles (coherent 8B loads), XOR-swizzled into LDS
        #pragma unroll
        for (int k = 0; k < 8; ++k) {
            int idx = (k << 10) + t;        // 0..8191 8B units
            int buf = idx >> 12;            // 0: pi->sp, 1: pj->sq
            int u   = idx & 4095;
            int row = u >> 6;               // 0..63
            int du  = u & 63;               // h0 = du*2
            int q   = du >> 1;
            int hi  = du & 1;
            int dq  = q ^ ((row >> 2) & 7);
            const float* src = (buf ? pjG + (size_t)(colb + row) * HH
                                    : piG + (size_t)(rowb + row) * HH) + (du << 1);
            float2 v = cload_f2(src);
            float* dst = (buf ? sq : sp) + row * HH + (dq << 2) + (hi << 1);
            *(float2*)dst = v;
        }
        if (t < HH) sw2[t] = W2[t];
        __syncthreads();

        // h split into 4 groups of 8 hq; each 256-thread group does a 4x4 micro-tile
        int hg = t >> 8, tt = t & 255;
        int w = tt >> 6, lane = tt & 63;
        int ti = ((w >> 1) << 3) + (lane >> 3);
        int tj = ((w & 1) << 3) + (lane & 7);
        int kti = ti & 7, ktj = tj & 7;

        float acc[4][4];
        #pragma unroll
        for (int a = 0; a < 4; ++a)
            #pragma unroll
            for (int c = 0; c < 4; ++c) acc[a][c] = 0.f;

        for (int hq = hg * 8; hq < hg * 8 + 8; ++hq) {
            float4 w4 = *(const float4*)(sw2 + (hq << 2));
            int offi = (hq ^ kti) << 2;
            int offj = (hq ^ ktj) << 2;
            float4 pa[4], pb[4];
            #pragma unroll
            for (int a = 0; a < 4; ++a) pa[a] = *(const float4*)(sp + (4*ti + a) * HH + offi);
            #pragma unroll
            for (int c = 0; c < 4; ++c) pb[c] = *(const float4*)(sq + (4*tj + c) * HH + offj);
            #pragma unroll
            for (int a = 0; a < 4; ++a) {
                #pragma unroll
                for (int c = 0; c < 4; ++c) {
                    float t0 = fmaxf(pa[a].x + pb[c].x, 0.f);
                    float t1 = fmaxf(pa[a].y + pb[c].y, 0.f);
                    float t2 = fmaxf(pa[a].z + pb[c].z, 0.f);
                    float t3 = fmaxf(pa[a].w + pb[c].w, 0.f);
                    float s = acc[a][c];
                    s += t0 * w4.x; s += t1 * w4.y; s += t2 * w4.z; s += t3 * w4.w;
                    acc[a][c] = s;
                }
            }
        }
        __syncthreads();                      // done with sp/sq
        float* cbuf = smem;                   // alias: [4 groups][256 tt][16]
        #pragma unroll
        for (int a = 0; a < 4; ++a)
            #pragma unroll
            for (int c = 0; c < 4; ++c)
                cbuf[(((hg << 8) + tt) << 4) + (a << 2) + c] = acc[a][c];
        __syncthreads();

        // combine h-groups + epilogue: thread -> (tt2, a2)
        int tt2 = t >> 2, a2 = t & 3;
        int w2_ = tt2 >> 6, lane2 = tt2 & 63;
        int ti2 = ((w2_ >> 1) << 3) + (lane2 >> 3);
        int tj2 = ((w2_ & 1) << 3) + (lane2 & 7);
        float4 o = make_float4(0.f, 0.f, 0.f, 0.f);
        #pragma unroll
        for (int g = 0; g < 4; ++g) {
            float4 pp = *(const float4*)(cbuf + (((g << 8) + tt2) << 4) + (a2 << 2));
            o.x += pp.x; o.y += pp.y; o.z += pp.z; o.w += pp.w;
        }
        int sl = slens[b];
        float bb2 = b2[0];
        int ig = i0 + 4 * ti2 + a2;
        int jb = j0 + 4 * tj2;
        float4 g4 = *(const float4*)(gum + ((size_t)(b * LL + ig)) * LL + jb);
        bool iv = ig < sl;
        float4 res;
        res.x = (iv && (jb + 0) < sl) ? (o.x + bb2 + g4.x) * 2.0f : NEGV;
        res.y = (iv && (jb + 1) < sl) ? (o.y + bb2 + g4.y) * 2.0f : NEGV;
        res.z = (iv && (jb + 2) < sl) ? (o.z + bb2 + g4.z) * 2.0f : NEGV;
        res.w = (iv && (jb + 3) < sl) ? (o.w + bb2 + g4.w) * 2.0f : NEGV;
        float* lap = laG + ((size_t)(b * LL + ig)) * LL + jb;
        cstore_f2(lap,     make_float2(res.x, res.y));
        cstore_f2(lap + 2, make_float2(res.z, res.w));
    }
    grid_barrier(cntA, 2 * NBLK);

    // ===================== Phase 2: 10 Sinkhorn iterations =====================
    if (bx >= NACT) return;

    const int b2i = bx >> 4;
    const int stripe = bx & 15;
    const int r0 = stripe << 5;               // 32 rows per active block
    float* sla  = smem;                       // [32][512]
    float* redm = smem + 16384;               // [2][512]
    float* reds = smem + 17408;               // [2][512]
    float* clse = smem + 18432;               // [512]
    const int sl_a = slens[b2i];
    float tyv = 0.f, tmv = 0.f;

    {
        const float* src = laG + (((size_t)(b2i << 9) + r0) << 9);
        #pragma unroll
        for (int k = 0; k < 8; ++k) {
            int u = (k << 10) + t;             // 8192 8B units = 32x512 floats
            float2 v = cload_f2(src + (u << 1));
            *(float2*)(sla + (u << 1)) = v;
        }
        __syncthreads();
    }

    for (int it = 0; it < 10; ++it) {
        const int par = it & 1;
        const int last = (it == 9);
        {
            // ---- row LSE (block-local; 32 lanes per row) ----
            int r = t >> 5, cq = t & 31;
            float4 v[4];
            #pragma unroll
            for (int k = 0; k < 4; ++k)
                v[k] = *(float4*)(sla + (r << 9) + ((cq + (k << 5)) << 2));
            float m = fmaxf(fmaxf(hmax4(v[0]), hmax4(v[1])), fmaxf(hmax4(v[2]), hmax4(v[3])));
            #pragma unroll
            for (int off = 16; off; off >>= 1) m = fmaxf(m, __shfl_xor(m, off));
            float s = 0.f;
            #pragma unroll
            for (int k = 0; k < 4; ++k)
                s += __expf(v[k].x - m) + __expf(v[k].y - m) + __expf(v[k].z - m) + __expf(v[k].w - m);
            #pragma unroll
            for (int off = 16; off; off >>= 1) s += __shfl_xor(s, off);
            float lse = m + __logf(s);        // NEG-absorption preserved in fp32
            #pragma unroll
            for (int k = 0; k < 4; ++k) {
                v[k].x -= lse; v[k].y -= lse; v[k].z -= lse; v[k].w -= lse;
                *(float4*)(sla + (r << 9) + ((cq + (k << 5)) << 2)) = v[k];
            }
            __syncthreads();

            // ---- column partials over this block's 32 rows (2 subs of 16) ----
            int c = t & 511, half = t >> 9;
            float vv[16];
            #pragma unroll
            for (int rr = 0; rr < 16; ++rr) vv[rr] = sla[(((half << 4) + rr) << 9) + c];
            float mp = vv[0];
            #pragma unroll
            for (int rr = 1; rr < 16; ++rr) mp = fmaxf(mp, vv[rr]);
            float spv = 0.f;
            #pragma unroll
            for (int rr = 0; rr < 16; ++rr) spv += __expf(vv[rr] - mp);
            size_t pidx = ((((size_t)par * BB + b2i) << 5) + (stripe << 1) + half) * LL + c;
            cstore_f2(cpkG + pidx * 2, make_float2(mp, spv));
        }
        grid_barrier(cntB, (it + 1) * NACT);
        {
            // ---- combine 32 sub-partials (deterministic, redundant per block) --
            int c = t & 511, half = t >> 9;
            const float* pB = cpkG + (((((size_t)par * BB + b2i) << 5)) * LL) * 2;
            int g0 = half << 4;
            float mreg[16], sreg[16];
            #pragma unroll
            for (int g = 0; g < 16; ++g) {
                float2 ms = cload_f2(pB + (size_t)((g0 + g) * LL + c) * 2);
                mreg[g] = ms.x; sreg[g] = ms.y;
            }
            float M = mreg[0];
            #pragma unroll
            for (int g = 1; g < 16; ++g) M = fmaxf(M, mreg[g]);
            redm[(half << 9) + c] = M;
            __syncthreads();
            float Mg = fmaxf(redm[c], redm[512 + c]);
            float S = 0.f;
            #pragma unroll
            for (int g = 0; g < 16; ++g)
                S = fmaf(sreg[g], __expf(mreg[g] - Mg), S);
            reds[(half << 9) + c] = S;
            __syncthreads();
            if (half == 0) clse[c] = Mg + __logf(reds[c] + reds[512 + c]);
            __syncthreads();

            // ---- subtract + re-mask (or finalize) ----
            int r = t >> 5, cq = t & 31;
            int grow = r0 + r;
            bool ivR = grow < sl_a;
            if (!last) {
                #pragma unroll
                for (int k = 0; k < 4; ++k) {
                    int cb = (cq + (k << 5)) << 2;
                    float4 v = *(float4*)(sla + (r << 9) + cb);
                    float4 l = *(const float4*)(clse + cb);
                    float4 o;
                    o.x = (ivR && (cb + 0) < sl_a) ? v.x - l.x : NEGV;
                    o.y = (ivR && (cb + 1) < sl_a) ? v.y - l.y : NEGV;
                    o.z = (ivR && (cb + 2) < sl_a) ? v.z - l.z : NEGV;
                    o.w = (ivR && (cb + 3) < sl_a) ? v.w - l.w : NEGV;
                    *(float4*)(sla + (r << 9) + cb) = o;
                }
            } else {
                float etf = (float)etype[(b2i << 9) + grow];
                float etv = etime[(b2i << 9) + grow];
                float4 p[4];
                #pragma unroll
                for (int k = 0; k < 4; ++k) {
                    int cb = (cq + (k << 5)) << 2;
                    float4 v = *(float4*)(sla + (r << 9) + cb);
                    float4 l = *(const float4*)(clse + cb);
                    float4 q;
                    q.x = (ivR && (cb + 0) < sl_a) ? __expf(v.x - l.x) : 0.f;
                    q.y = (ivR && (cb + 1) < sl_a) ? __expf(v.y - l.y) : 0.f;
                    q.z = (ivR && (cb + 2) < sl_a) ? __expf(v.z - l.z) : 0.f;
                    q.w = (ivR && (cb + 3) < sl_a) ? __expf(v.w - l.w) : 0.f;
                    p[k] = q;
                    // perm output: read only by the harness after kernel end
                    *(float4*)(out + 2 * BB * LL + (((size_t)(b2i << 9) + grow) << 9) + cb) = q;
                }
                // type-weighted column partial (transpose via sla)
                #pragma unroll
                for (int k = 0; k < 4; ++k) {
                    int cb = (cq + (k << 5)) << 2;
                    *(float4*)(sla + (r << 9) + cb) =
                        make_float4(p[k].x * etf, p[k].y * etf, p[k].z * etf, p[k].w * etf);
                }
                __syncthreads();
                {
                    int c2 = t & 511, h2 = t >> 9;
                    float sA = 0.f;
                    #pragma unroll
                    for (int rr = 0; rr < 16; ++rr) sA += sla[(((h2 << 4) + rr) << 9) + c2];
                    redm[(h2 << 9) + c2] = sA;
                }
                __syncthreads();
                if (t < 512) tyv = redm[t] + redm[512 + t];
                __syncthreads();
                // time-weighted column partial
                #pragma unroll
                for (int k = 0; k < 4; ++k) {
                    int cb = (cq + (k << 5)) << 2;
                    *(float4*)(sla + (r << 9) + cb) =
                        make_float4(p[k].x * etv, p[k].y * etv, p[k].z * etv, p[k].w * etv);
                }
                __syncthreads();
                {
                    int c2 = t & 511, h2 = t >> 9;
                    float sB = 0.f;
                    #pragma unroll
                    for (int rr = 0; rr < 16; ++rr) sB += sla[(((h2 << 4) + rr) << 9) + c2];
                    reds[(h2 << 9) + c2] = sB;
                }
                __syncthreads();
                if (t < 512) {
                    tmv = reds[t] + reds[512 + t];
                    cstore_f2(poutG + (size_t)(((b2i << 4) + stripe) * LL + t) * 2,
                              make_float2(tyv, tmv));
                }
            }
        }
    }
    grid_barrier(cntB, 11 * NACT);

    // ===================== Phase 3: combine output partials ====================
    if (t < 32) {
        int b = bx >> 4, chunk = bx & 15;
        int c = (chunk << 5) + t;
        float a = 0.f, d = 0.f;
        #pragma unroll
        for (int s = 0; s < 16; ++s) {
            float2 p = cload_f2(poutG + (size_t)(((b << 4) + s) * LL + c) * 2);
            a += p.x; d += p.y;
        }
        out[(b << 9) + c] = a;                 // types_permed
        out[BB * LL + (b << 9) + c] = d;       // times_permed
    }
}

extern "C" void kernel_launch(void* const* d_in, const int* in_sizes, int n_in,
                              void* d_out, int out_size, void* d_ws, size_t ws_size,
                              hipStream_t stream)
{
    const float* etime = (const float*)d_in[0];
    const int*   etype = (const int*)d_in[1];
    const float* x     = (const float*)d_in[2];
    const int*   slens = (const int*)d_in[3];
    const float* gum   = (const float*)d_in[4];
    const float* W1    = (const float*)d_in[5];
    const float* b1    = (const float*)d_in[6];
    const float* W2    = (const float*)d_in[7];
    const float* b2    = (const float*)d_in[8];
    float* out = (float*)d_out;
    float* wsf = (float*)d_ws;

    // reset the grid-barrier counters (deterministic across graph replays)
    hipMemsetAsync(d_ws, 0, 256, stream);

    void* args[] = {(void*)&etime, (void*)&etype, (void*)&x, (void*)&slens, (void*)&gum,
                    (void*)&W1, (void*)&b1, (void*)&W2, (void*)&b2, (void*)&out, (void*)&wsf};
    hipError_t err = hipLaunchCooperativeKernel((const void*)mega, dim3(NBLK), dim3(NTHR),
                                                args, 0, stream);
    if (err != hipSuccess) {
        // 256 blocks x 1024 thr = exactly 1 block/CU on 256 CUs -> co-resident.
        mega<<<NBLK, NTHR, 0, stream>>>(etime, etype, x, slens, gum, W1, b1, W2, b2, out, wsf);
    }
}

// Round 7
// 125.315 us; speedup vs baseline: 2.6861x; 1.1128x over previous
//
#include <hip/hip_runtime.h>
#include <cstdint>

#define BB 4
#define LL 512
#define DD 64
#define HH 128
#define NEGV -1000000000.0f
#define NBLK 256
#define NTHR 1024
#define NACT 64   // blocks active during sinkhorn iterations (16 per batch, 32 rows each)

// ---------------------------------------------------------------------------
// Coherent (write-through / read-through) 8B accessors. Relaxed agent-scope
// atomics lower to global_load/store_dwordx2 sc0 sc1 — bypass the non-coherent
// per-XCD L2, hit the chip-coherent L3. ALL cross-block data moves through
// these, so barriers need NO buffer_wbl2/buffer_inv (round-5's 13us/barrier).
// ---------------------------------------------------------------------------
union U8 { unsigned long long u; float2 f; };

__device__ __forceinline__ float2 cload_f2(const float* p) {
    U8 v;
    v.u = __hip_atomic_load((const unsigned long long*)p,
                            __ATOMIC_RELAXED, __HIP_MEMORY_SCOPE_AGENT);
    return v.f;
}
__device__ __forceinline__ void cstore_f2(float* p, float2 x) {
    U8 v; v.f = x;
    __hip_atomic_store((unsigned long long*)p, v.u,
                       __ATOMIC_RELAXED, __HIP_MEMORY_SCOPE_AGENT);
}

// Light grid barrier: __syncthreads drains vmcnt (sc1 store ack = visible at
// L3), leader relaxed fetch_add + relaxed polls; workgroup fences are
// waitcnt-only (compiler ordering, no cache maintenance).
__device__ __forceinline__ void grid_barrier(unsigned* cnt, unsigned target) {
    __builtin_amdgcn_fence(__ATOMIC_RELEASE, "workgroup");
    __syncthreads();
    if (threadIdx.x == 0) {
        __hip_atomic_fetch_add(cnt, 1u, __ATOMIC_RELAXED, __HIP_MEMORY_SCOPE_AGENT);
        while (__hip_atomic_load(cnt, __ATOMIC_RELAXED, __HIP_MEMORY_SCOPE_AGENT) < target)
            __builtin_amdgcn_s_sleep(1);
    }
    __builtin_amdgcn_fence(__ATOMIC_ACQUIRE, "workgroup");
    __syncthreads();
}

__device__ __forceinline__ float hmax4(float4 v) {
    return fmaxf(fmaxf(v.x, v.y), fmaxf(v.z, v.w));
}

__global__ __launch_bounds__(NTHR) void mega(
    const float* __restrict__ etime, const int* __restrict__ etype,
    const float* __restrict__ x, const int* __restrict__ slens,
    const float* __restrict__ gum, const float* __restrict__ W1,
    const float* __restrict__ b1, const float* __restrict__ W2,
    const float* __restrict__ b2, float* __restrict__ out, float* __restrict__ ws)
{
    // LDS map (floats):
    //   [0,16384)      phase1: sp(8192)+sq(8192); then cbuf(16384); phase2: sla 32x512
    //   [16384,17408)  redm [2][512]
    //   [17408,18432)  reds [2][512]
    //   [18432,18944)  clse [512]
    //   [18944,19072)  sw2  [128]
    __shared__ float smem[19072];

    // ws words 0..127 reserved for barrier counters (memset 512B per replay):
    //   word 0: cntA (all-256-block barriers, phases 0/1)
    //   word 16+16*b: per-batch counters (16-block iteration barriers)
    unsigned* cntA = (unsigned*)ws;
    float* piG   = ws + 128;                       // [2048][128]
    float* pjG   = piG + BB * LL * HH;             // [2048][128]
    float* laG   = pjG + BB * LL * HH;             // [4][512][512]
    float* cpkG  = laG + (size_t)BB * LL * LL;     // [2][4][16][512] x (m,s) pairs
    float* poutG = cpkG + (size_t)2 * BB * 16 * LL * 2; // [4][16][512] x (ty,tm)

    const int t = threadIdx.x;
    const int bx = blockIdx.x;

    // ===================== Phase 0: pi = x@W1[:D]+b1, pj = x@W1[D:] ============
    {
        int gid = (bx << 10) + t;
        int arr = gid >> 17;               // 0: pi, 1: pj
        int rem = gid & 131071;
        int row = rem >> 6;                // 0..2047
        int h0  = (rem & 63) << 1;
        const float* xr = x + row * DD;
        const float* wb = W1 + (size_t)(arr * DD) * HH + h0;
        float a0 = arr ? 0.f : b1[h0];
        float a1 = arr ? 0.f : b1[h0 + 1];
        #pragma unroll 8
        for (int d = 0; d < DD; ++d) {
            float xv = xr[d];
            a0 = fmaf(xv, wb[d * HH + 0], a0);
            a1 = fmaf(xv, wb[d * HH + 1], a1);
        }
        float* dst = (arr ? pjG : piG) + (size_t)row * HH + h0;
        cstore_f2(dst, make_float2(a0, a1));
    }
    grid_barrier(cntA, 1 * NBLK);

    // ===================== Phase 1: scores -> la0 (masked, /tau) ===============
    {
        float* sp  = smem;
        float* sq  = smem + 8192;
        float* sw2 = smem + 18944;
        int jt = bx & 7, it8 = (bx >> 3) & 7, b = bx >> 6;
        int i0 = it8 << 6, j0 = jt << 6;
        int rowb = b * LL + i0, colb = b * LL + j0;

        // stage pi/pj tiles (coherent 8B loads), XOR-swizzled into LDS
        #pragma unroll
        for (int k = 0; k < 8; ++k) {
            int idx = (k << 10) + t;        // 0..8191 8B units
            int buf = idx >> 12;            // 0: pi->sp, 1: pj->sq
            int u   = idx & 4095;
            int row = u >> 6;               // 0..63
            int du  = u & 63;               // h0 = du*2
            int q   = du >> 1;
            int hi  = du & 1;
            int dq  = q ^ ((row >> 2) & 7);
            const float* src = (buf ? pjG + (size_t)(colb + row) * HH
                                    : piG + (size_t)(rowb + row) * HH) + (du << 1);
            float2 v = cload_f2(src);
            float* dst = (buf ? sq : sp) + row * HH + (dq << 2) + (hi << 1);
            *(float2*)dst = v;
        }
        if (t < HH) sw2[t] = W2[t];
        __syncthreads();

        int hg = t >> 8, tt = t & 255;
        int w = tt >> 6, lane = tt & 63;
        int ti = ((w >> 1) << 3) + (lane >> 3);
        int tj = ((w & 1) << 3) + (lane & 7);
        int kti = ti & 7, ktj = tj & 7;

        float acc[4][4];
        #pragma unroll
        for (int a = 0; a < 4; ++a)
            #pragma unroll
            for (int c = 0; c < 4; ++c) acc[a][c] = 0.f;

        for (int hq = hg * 8; hq < hg * 8 + 8; ++hq) {
            float4 w4 = *(const float4*)(sw2 + (hq << 2));
            int offi = (hq ^ kti) << 2;
            int offj = (hq ^ ktj) << 2;
            float4 pa[4], pb[4];
            #pragma unroll
            for (int a = 0; a < 4; ++a) pa[a] = *(const float4*)(sp + (4*ti + a) * HH + offi);
            #pragma unroll
            for (int c = 0; c < 4; ++c) pb[c] = *(const float4*)(sq + (4*tj + c) * HH + offj);
            #pragma unroll
            for (int a = 0; a < 4; ++a) {
                #pragma unroll
                for (int c = 0; c < 4; ++c) {
                    float t0 = fmaxf(pa[a].x + pb[c].x, 0.f);
                    float t1 = fmaxf(pa[a].y + pb[c].y, 0.f);
                    float t2 = fmaxf(pa[a].z + pb[c].z, 0.f);
                    float t3 = fmaxf(pa[a].w + pb[c].w, 0.f);
                    float s = acc[a][c];
                    s += t0 * w4.x; s += t1 * w4.y; s += t2 * w4.z; s += t3 * w4.w;
                    acc[a][c] = s;
                }
            }
        }
        __syncthreads();                      // done with sp/sq
        float* cbuf = smem;                   // alias: [4 groups][256 tt][16]
        #pragma unroll
        for (int a = 0; a < 4; ++a)
            #pragma unroll
            for (int c = 0; c < 4; ++c)
                cbuf[(((hg << 8) + tt) << 4) + (a << 2) + c] = acc[a][c];
        __syncthreads();

        int tt2 = t >> 2, a2 = t & 3;
        int w2_ = tt2 >> 6, lane2 = tt2 & 63;
        int ti2 = ((w2_ >> 1) << 3) + (lane2 >> 3);
        int tj2 = ((w2_ & 1) << 3) + (lane2 & 7);
        float4 o = make_float4(0.f, 0.f, 0.f, 0.f);
        #pragma unroll
        for (int g = 0; g < 4; ++g) {
            float4 pp = *(const float4*)(cbuf + (((g << 8) + tt2) << 4) + (a2 << 2));
            o.x += pp.x; o.y += pp.y; o.z += pp.z; o.w += pp.w;
        }
        int sl = slens[b];
        float bb2 = b2[0];
        int ig = i0 + 4 * ti2 + a2;
        int jb = j0 + 4 * tj2;
        float4 g4 = *(const float4*)(gum + ((size_t)(b * LL + ig)) * LL + jb);
        bool iv = ig < sl;
        float4 res;
        res.x = (iv && (jb + 0) < sl) ? (o.x + bb2 + g4.x) * 2.0f : NEGV;
        res.y = (iv && (jb + 1) < sl) ? (o.y + bb2 + g4.y) * 2.0f : NEGV;
        res.z = (iv && (jb + 2) < sl) ? (o.z + bb2 + g4.z) * 2.0f : NEGV;
        res.w = (iv && (jb + 3) < sl) ? (o.w + bb2 + g4.w) * 2.0f : NEGV;
        float* lap = laG + ((size_t)(b * LL + ig)) * LL + jb;
        cstore_f2(lap,     make_float2(res.x, res.y));
        cstore_f2(lap + 2, make_float2(res.z, res.w));
    }
    grid_barrier(cntA, 2 * NBLK);

    // ===================== Phase 2: 10 Sinkhorn iterations =====================
    if (bx >= NACT) return;

    const int b2i = bx >> 4;
    const int stripe = bx & 15;
    const int r0 = stripe << 5;               // 32 rows per active block
    unsigned* cntB = (unsigned*)ws + 16 + (b2i << 4);  // per-batch counter
    float* sla  = smem;                       // [32][512]
    float* redm = smem + 16384;               // [2][512]
    float* reds = smem + 17408;               // [2][512]
    float* clse = smem + 18432;               // [512]
    const int sl_a = slens[b2i];
    float tyv = 0.f, tmv = 0.f;

    {
        const float* src = laG + (((size_t)(b2i << 9) + r0) << 9);
        #pragma unroll
        for (int k = 0; k < 8; ++k) {
            int u = (k << 10) + t;             // 8192 8B units = 32x512 floats
            float2 v = cload_f2(src + (u << 1));
            *(float2*)(sla + (u << 1)) = v;
        }
        __syncthreads();
    }

    for (int it = 0; it < 10; ++it) {
        const int par = it & 1;
        const int last = (it == 9);
        {
            // ---- row LSE (block-local; 32 lanes per row) ----
            int r = t >> 5, cq = t & 31;
            float4 v[4];
            #pragma unroll
            for (int k = 0; k < 4; ++k)
                v[k] = *(float4*)(sla + (r << 9) + ((cq + (k << 5)) << 2));
            float m = fmaxf(fmaxf(hmax4(v[0]), hmax4(v[1])), fmaxf(hmax4(v[2]), hmax4(v[3])));
            #pragma unroll
            for (int off = 16; off; off >>= 1) m = fmaxf(m, __shfl_xor(m, off));
            float s = 0.f;
            #pragma unroll
            for (int k = 0; k < 4; ++k)
                s += __expf(v[k].x - m) + __expf(v[k].y - m) + __expf(v[k].z - m) + __expf(v[k].w - m);
            #pragma unroll
            for (int off = 16; off; off >>= 1) s += __shfl_xor(s, off);
            float lse = m + __logf(s);        // NEG-absorption preserved in fp32
            #pragma unroll
            for (int k = 0; k < 4; ++k) {
                v[k].x -= lse; v[k].y -= lse; v[k].z -= lse; v[k].w -= lse;
                *(float4*)(sla + (r << 9) + ((cq + (k << 5)) << 2)) = v[k];
            }
            __syncthreads();

            // ---- column partials over 32 rows: per-half (m,s), pre-combined
            //      in LDS to ONE partial per (block, col) before the store ----
            int c = t & 511, half = t >> 9;
            float vv[16];
            #pragma unroll
            for (int rr = 0; rr < 16; ++rr) vv[rr] = sla[(((half << 4) + rr) << 9) + c];
            float mp = vv[0];
            #pragma unroll
            for (int rr = 1; rr < 16; ++rr) mp = fmaxf(mp, vv[rr]);
            float spv = 0.f;
            #pragma unroll
            for (int rr = 0; rr < 16; ++rr) spv += __expf(vv[rr] - mp);
            redm[(half << 9) + c] = mp;
            reds[(half << 9) + c] = spv;
            __syncthreads();
            if (half == 0) {
                float m1 = redm[512 + c], s1 = reds[512 + c];
                float M = fmaxf(mp, m1);
                float S = fmaf(spv, __expf(mp - M), s1 * __expf(m1 - M));
                cstore_f2(cpkG + (size_t)(((((par * BB) + b2i) << 4) + stripe) * LL + c) * 2,
                          make_float2(M, S));
            }
        }
        grid_barrier(cntB, (it + 1) * 16);
        {
            // ---- combine 16 partials (8 per half-thread, redundant per block) --
            int c = t & 511, half = t >> 9;
            const float* pB = cpkG + (size_t)((((par * BB) + b2i) << 4) * LL) * 2;
            int g0 = half << 3;
            float mreg[8], sreg[8];
            #pragma unroll
            for (int g = 0; g < 8; ++g) {
                float2 ms = cload_f2(pB + (size_t)((g0 + g) * LL + c) * 2);
                mreg[g] = ms.x; sreg[g] = ms.y;
            }
            float M8 = mreg[0];
            #pragma unroll
            for (int g = 1; g < 8; ++g) M8 = fmaxf(M8, mreg[g]);
            redm[(half << 9) + c] = M8;
            __syncthreads();
            float Mg = fmaxf(redm[c], redm[512 + c]);
            float S8 = 0.f;
            #pragma unroll
            for (int g = 0; g < 8; ++g)
                S8 = fmaf(sreg[g], __expf(mreg[g] - Mg), S8);
            reds[(half << 9) + c] = S8;
            __syncthreads();
            if (half == 0) clse[c] = Mg + __logf(reds[c] + reds[512 + c]);
            __syncthreads();

            // ---- subtract + re-mask (or finalize) ----
            int r = t >> 5, cq = t & 31;
            int grow = r0 + r;
            bool ivR = grow < sl_a;
            if (!last) {
                #pragma unroll
                for (int k = 0; k < 4; ++k) {
                    int cb = (cq + (k << 5)) << 2;
                    float4 v = *(float4*)(sla + (r << 9) + cb);
                    float4 l = *(const float4*)(clse + cb);
                    float4 o;
                    o.x = (ivR && (cb + 0) < sl_a) ? v.x - l.x : NEGV;
                    o.y = (ivR && (cb + 1) < sl_a) ? v.y - l.y : NEGV;
                    o.z = (ivR && (cb + 2) < sl_a) ? v.z - l.z : NEGV;
                    o.w = (ivR && (cb + 3) < sl_a) ? v.w - l.w : NEGV;
                    *(float4*)(sla + (r << 9) + cb) = o;
                }
            } else {
                float etf = (float)etype[(b2i << 9) + grow];
                float etv = etime[(b2i << 9) + grow];
                float4 p[4];
                #pragma unroll
                for (int k = 0; k < 4; ++k) {
                    int cb = (cq + (k << 5)) << 2;
                    float4 v = *(float4*)(sla + (r << 9) + cb);
                    float4 l = *(const float4*)(clse + cb);
                    float4 q;
                    q.x = (ivR && (cb + 0) < sl_a) ? __expf(v.x - l.x) : 0.f;
                    q.y = (ivR && (cb + 1) < sl_a) ? __expf(v.y - l.y) : 0.f;
                    q.z = (ivR && (cb + 2) < sl_a) ? __expf(v.z - l.z) : 0.f;
                    q.w = (ivR && (cb + 3) < sl_a) ? __expf(v.w - l.w) : 0.f;
                    p[k] = q;
                    *(float4*)(out + 2 * BB * LL + (((size_t)(b2i << 9) + grow) << 9) + cb) = q;
                }
                // type-weighted column partial (transpose via sla)
                #pragma unroll
                for (int k = 0; k < 4; ++k) {
                    int cb = (cq + (k << 5)) << 2;
                    *(float4*)(sla + (r << 9) + cb) =
                        make_float4(p[k].x * etf, p[k].y * etf, p[k].z * etf, p[k].w * etf);
                }
                __syncthreads();
                {
                    int c2 = t & 511, h2 = t >> 9;
                    float sA = 0.f;
                    #pragma unroll
                    for (int rr = 0; rr < 16; ++rr) sA += sla[(((h2 << 4) + rr) << 9) + c2];
                    redm[(h2 << 9) + c2] = sA;
                }
                __syncthreads();
                if (t < 512) tyv = redm[t] + redm[512 + t];
                __syncthreads();
                // time-weighted column partial
                #pragma unroll
                for (int k = 0; k < 4; ++k) {
                    int cb = (cq + (k << 5)) << 2;
                    *(float4*)(sla + (r << 9) + cb) =
                        make_float4(p[k].x * etv, p[k].y * etv, p[k].z * etv, p[k].w * etv);
                }
                __syncthreads();
                {
                    int c2 = t & 511, h2 = t >> 9;
                    float sB = 0.f;
                    #pragma unroll
                    for (int rr = 0; rr < 16; ++rr) sB += sla[(((h2 << 4) + rr) << 9) + c2];
                    reds[(h2 << 9) + c2] = sB;
                }
                __syncthreads();
                if (t < 512) {
                    tmv = reds[t] + reds[512 + t];
                    cstore_f2(poutG + (size_t)(((b2i << 4) + stripe) * LL + t) * 2,
                              make_float2(tyv, tmv));
                }
            }
        }
    }
    grid_barrier(cntB, 11 * 16);

    // ===================== Phase 3: combine output partials (per batch) ========
    if (t < 32) {
        int c = (stripe << 5) + t;
        float a = 0.f, d = 0.f;
        #pragma unroll
        for (int s = 0; s < 16; ++s) {
            float2 p = cload_f2(poutG + (size_t)(((b2i << 4) + s) * LL + c) * 2);
            a += p.x; d += p.y;
        }
        out[(b2i << 9) + c] = a;                 // types_permed
        out[BB * LL + (b2i << 9) + c] = d;       // times_permed
    }
}

extern "C" void kernel_launch(void* const* d_in, const int* in_sizes, int n_in,
                              void* d_out, int out_size, void* d_ws, size_t ws_size,
                              hipStream_t stream)
{
    const float* etime = (const float*)d_in[0];
    const int*   etype = (const int*)d_in[1];
    const float* x     = (const float*)d_in[2];
    const int*   slens = (const int*)d_in[3];
    const float* gum   = (const float*)d_in[4];
    const float* W1    = (const float*)d_in[5];
    const float* b1    = (const float*)d_in[6];
    const float* W2    = (const float*)d_in[7];
    const float* b2    = (const float*)d_in[8];
    float* out = (float*)d_out;
    float* wsf = (float*)d_ws;

    // reset all barrier counters (words 0..127) deterministically per replay
    hipMemsetAsync(d_ws, 0, 512, stream);

    void* args[] = {(void*)&etime, (void*)&etype, (void*)&x, (void*)&slens, (void*)&gum,
                    (void*)&W1, (void*)&b1, (void*)&W2, (void*)&b2, (void*)&out, (void*)&wsf};
    hipError_t err = hipLaunchCooperativeKernel((const void*)mega, dim3(NBLK), dim3(NTHR),
                                                args, 0, stream);
    if (err != hipSuccess) {
        // 256 blocks x 1024 thr, 76KB LDS -> exactly 1 block/CU on 256 CUs.
        mega<<<NBLK, NTHR, 0, stream>>>(etime, etype, x, slens, gum, W1, b1, W2, b2, out, wsf);
    }
}